// Round 6
// baseline (5198.563 us; speedup 1.0000x reference)
//
#include <hip/hip_runtime.h>
#include <hip/hip_bf16.h>
#include <math.h>

#define SEQ 512
#define NB  128
#define NIN 512
#define NH  1024

typedef __attribute__((ext_vector_type(8))) short short8;
typedef __attribute__((ext_vector_type(4))) float f32x4;
typedef __attribute__((ext_vector_type(4))) unsigned int u32x4;
typedef unsigned long long u64;

__device__ __forceinline__ unsigned short bf16b(float f) {
  __hip_bfloat16 h = __float2bfloat16(f);
  return *reinterpret_cast<unsigned short*>(&h);
}
__device__ __forceinline__ short8 cvt8(u32x4 u) { return __builtin_bit_cast(short8, u); }

// ---- Wh fp32 [NH][NH] -> WhT bf16 [c][k] ----
__global__ void k_cvt_whT(const float* __restrict__ wh, unsigned short* __restrict__ whT) {
  int idx = blockIdx.x * 256 + threadIdx.x;
  int k = idx >> 10, c = idx & (NH - 1);
  whT[(size_t)c * NH + k] = bf16b(wh[idx]);
}

// ---- Wx fp32 [NIN][NH] -> WxT bf16 [c][k] ----
__global__ void k_cvt_wxT(const float* __restrict__ wx, unsigned short* __restrict__ wxT) {
  int idx = blockIdx.x * 256 + threadIdx.x;
  int k = idx >> 10, c = idx & (NH - 1);
  wxT[(size_t)c * NIN + k] = bf16b(wx[idx]);
}

// ---- initial_state fp32 [NB][NH] -> fragment-packed bf16 state (layout v1) ----
// element (row,k) -> chunk (mg=row>>4, kc=k>>5); lane ln=(row&15)|(((k&31)>>3)<<4); elem i=k&7
__global__ void k_init_state(const float* __restrict__ s0, unsigned short* __restrict__ sbuf) {
  int idx = blockIdx.x * 256 + threadIdx.x;
  int row = idx >> 10, k = idx & (NH - 1);
  int mg = row >> 4, kc = k >> 5, g = (k & 31) >> 3, i = k & 7;
  int ln = (row & 15) | (g << 4);
  sbuf[((size_t)(mg * 32 + kc) * 64 + ln) * 8 + i] = bf16b(s0[idx]);
}

// ---- Phase 1: xw = input @ Wx + bias  -> fp32 into d_out states region ----
__launch_bounds__(256)
__global__ void k_xw_gemm(const float* __restrict__ x, const unsigned short* __restrict__ wxT,
                          const float* __restrict__ bias, float* __restrict__ out) {
  __shared__ unsigned short a_lds[128 * 40];
  __shared__ unsigned short b_lds[128 * 40];
  const int bx = blockIdx.x;
  const int n0 = (bx & 7) * 128;
  const int m0 = (bx >> 3) * 128;
  const int tid = threadIdx.x, lane = tid & 63, w = tid >> 6;
  const int wr = w >> 1, wc = w & 1;
  f32x4 acc[4][4] = {};
  for (int k0 = 0; k0 < NIN; k0 += 32) {
    {
      int j = tid & 7, rr = tid >> 3;
      #pragma unroll
      for (int p = 0; p < 4; ++p) {
        int row = p * 32 + rr;
        const float4 v = *reinterpret_cast<const float4*>(&x[(size_t)(m0 + row) * NIN + k0 + 4 * j]);
        unsigned int lo = bf16b(v.x) | ((unsigned int)bf16b(v.y) << 16);
        unsigned int hi = bf16b(v.z) | ((unsigned int)bf16b(v.w) << 16);
        *reinterpret_cast<uint2*>(&a_lds[row * 40 + 4 * j]) = make_uint2(lo, hi);
      }
    }
    {
      #pragma unroll
      for (int p = 0; p < 2; ++p) {
        int tt = p * 256 + tid;
        int col = tt >> 2, ko = (tt & 3) * 8;
        const uint4 v = *reinterpret_cast<const uint4*>(&wxT[(size_t)(n0 + col) * NIN + k0 + ko]);
        *reinterpret_cast<uint4*>(&b_lds[col * 40 + ko]) = v;
      }
    }
    __syncthreads();
    short8 af[4], bf[4];
    #pragma unroll
    for (int bi = 0; bi < 4; ++bi)
      af[bi] = *reinterpret_cast<const short8*>(&a_lds[(wr * 64 + bi * 16 + (lane & 15)) * 40 + (lane >> 4) * 8]);
    #pragma unroll
    for (int bj = 0; bj < 4; ++bj)
      bf[bj] = *reinterpret_cast<const short8*>(&b_lds[(wc * 64 + bj * 16 + (lane & 15)) * 40 + (lane >> 4) * 8]);
    #pragma unroll
    for (int bi = 0; bi < 4; ++bi) {
      #pragma unroll
      for (int bj = 0; bj < 4; ++bj)
        acc[bi][bj] = __builtin_amdgcn_mfma_f32_16x16x32_bf16(af[bi], bf[bj], acc[bi][bj], 0, 0, 0);
    }
    __syncthreads();
  }
  #pragma unroll
  for (int bi = 0; bi < 4; ++bi) {
    #pragma unroll
    for (int bj = 0; bj < 4; ++bj) {
      int col = n0 + wc * 64 + bj * 16 + (lane & 15);
      float bv = bias[col];
      #pragma unroll
      for (int r = 0; r < 4; ++r) {
        int row = m0 + wr * 64 + bi * 16 + (lane >> 4) * 4 + r;
        out[(size_t)row * NH + col] = acc[bi][bj][r] + bv;
      }
    }
  }
}

#define A_LOAD(p) __hip_atomic_load((p), __ATOMIC_RELAXED, __HIP_MEMORY_SCOPE_AGENT)

// ---- Phase 2: persistent scan. Wave = 32 rows x 16 cols; Wh register-stationary.
// Coherent exchange via compiler-managed u64 agent-scope atomics; per-wave epoch flags.
// __syncthreads() between LDS repack write and read (ordering fence — r2-proven).
__launch_bounds__(256, 1)
__global__ void k_scan(const unsigned short* __restrict__ whT,
                       float* __restrict__ out,
                       unsigned short* __restrict__ sb0,
                       unsigned short* __restrict__ sb1,
                       unsigned int* __restrict__ flags) {
  __shared__ unsigned short r_lds[4 * 512];   // 1KB per wave, wave-local repack
  const int bx = blockIdx.x;
  const int bg = bx >> 5;    // batch group: 64 rows
  const int cg = bx & 31;    // column group: 32 cols
  const int tid = threadIdx.x, lane = tid & 63, w = tid >> 6;
  const int rg = w >> 1;     // row half within block
  const int cgl = w & 1;     // col half within block
  const int c0 = lane & 15, r0 = (lane >> 4) * 4;

  // ---- persistent B: this wave's 16 cols x K=1024, 128 VGPRs ----
  u32x4 breg[32];
  const int colC = cg * 32 + cgl * 16 + c0;
  {
    const unsigned short* bp = whT + (size_t)colC * NH + (lane >> 4) * 8;
    #pragma unroll
    for (int kc = 0; kc < 32; ++kc)
      breg[kc] = *reinterpret_cast<const u32x4*>(bp + kc * 32);
  }

  const int mgA = bg * 4 + rg * 2;                             // first of wave's two m-groups
  const size_t aBase = ((size_t)(mgA * 32) * 64 + lane) * 2;   // u64 units
  const int ldsRdU = w * 512 + (lane >> 5) * 256 + (lane & 31) * 8;   // ushort idx
  const size_t sIdx64 = (size_t)((mgA + (lane >> 5)) * 32 + cg) * 128 + (cgl * 32 + (lane & 31)) * 2;
  const int flagIdx = bg * 256 + cg * 4 + w;             // dword idx
  const int pollIdx = bg * 128 + lane;                   // u64 idx (2 flags/lane)
  const int rowBase = bg * 64 + rg * 32;

  // prologue: xw for t=0
  float xwreg[2][4];
  #pragma unroll
  for (int mf = 0; mf < 2; ++mf)
    #pragma unroll
    for (int r = 0; r < 4; ++r)
      xwreg[mf][r] = out[(size_t)(rowBase + mf * 16 + r0 + r) * NH + colC];

  #pragma unroll 1
  for (int t = 0; t < SEQ; ++t) {
    const u64* cur64 = (const u64*)((t & 1) ? sb1 : sb0);
    u64* nxt64 = (u64*)((t & 1) ? sb0 : sb1);

    // ---- A loads (coherent, compiler-managed) + MFMA, 4 independent chains ----
    f32x4 accE0 = {0.f,0.f,0.f,0.f}, accO0 = {0.f,0.f,0.f,0.f};
    f32x4 accE1 = {0.f,0.f,0.f,0.f}, accO1 = {0.f,0.f,0.f,0.f};
    #pragma unroll
    for (int kc = 0; kc < 32; ++kc) {
      const u64* p0 = cur64 + aBase + (size_t)kc * 128;   // mf = 0
      const u64* p1 = p0 + 4096;                          // mf = 1
      u64 lo0 = A_LOAD(p0);
      u64 hi0 = A_LOAD(p0 + 1);
      u64 lo1 = A_LOAD(p1);
      u64 hi1 = A_LOAD(p1 + 1);
      u32x4 u0; u0[0] = (unsigned)lo0; u0[1] = (unsigned)(lo0 >> 32); u0[2] = (unsigned)hi0; u0[3] = (unsigned)(hi0 >> 32);
      u32x4 u1; u1[0] = (unsigned)lo1; u1[1] = (unsigned)(lo1 >> 32); u1[2] = (unsigned)hi1; u1[3] = (unsigned)(hi1 >> 32);
      if (kc & 1) {
        accO0 = __builtin_amdgcn_mfma_f32_16x16x32_bf16(cvt8(u0), cvt8(breg[kc]), accO0, 0, 0, 0);
        accO1 = __builtin_amdgcn_mfma_f32_16x16x32_bf16(cvt8(u1), cvt8(breg[kc]), accO1, 0, 0, 0);
      } else {
        accE0 = __builtin_amdgcn_mfma_f32_16x16x32_bf16(cvt8(u0), cvt8(breg[kc]), accE0, 0, 0, 0);
        accE1 = __builtin_amdgcn_mfma_f32_16x16x32_bf16(cvt8(u1), cvt8(breg[kc]), accE1, 0, 0, 0);
      }
    }

    // ---- tanh + wave-local LDS repack write ----
    float vout[2][4];
    const int gc = c0 >> 3;
    #pragma unroll
    for (int mf = 0; mf < 2; ++mf) {
      const f32x4 s = (mf ? accE1 : accE0) + (mf ? accO1 : accO0);
      #pragma unroll
      for (int r = 0; r < 4; ++r) {
        float pre = s[r] + xwreg[mf][r];
        float e = __expf(2.0f * pre);
        float v = 1.0f - __fdividef(2.0f, e + 1.0f);
        vout[mf][r] = v;
        r_lds[w * 512 + mf * 256 + (((r0 + r) | (gc << 4)) << 3) + (c0 & 7)] = bf16b(v);
      }
    }
    // ordering fence between ushort repack-writes and u64 repack-read
    __syncthreads();
    const u64* rl = reinterpret_cast<const u64*>(&r_lds[ldsRdU]);
    u64 sd0 = rl[0], sd1 = rl[1];

    // ---- coherent state store, drain, flag ----
    __hip_atomic_store(nxt64 + sIdx64,     sd0, __ATOMIC_RELAXED, __HIP_MEMORY_SCOPE_AGENT);
    __hip_atomic_store(nxt64 + sIdx64 + 1, sd1, __ATOMIC_RELAXED, __HIP_MEMORY_SCOPE_AGENT);
    asm volatile("s_waitcnt vmcnt(0)" ::: "memory");
    if (t + 1 < SEQ) {
      if (lane == 0)
        __hip_atomic_store(flags + flagIdx, (unsigned)(t + 1),
                           __ATOMIC_RELAXED, __HIP_MEMORY_SCOPE_AGENT);
    }

    // ---- fp32 out stores + xw[t+1] prefetch (hidden in barrier window) ----
    #pragma unroll
    for (int mf = 0; mf < 2; ++mf)
      #pragma unroll
      for (int r = 0; r < 4; ++r)
        out[((size_t)t * NB + rowBase + mf * 16 + r0 + r) * NH + colC] = vout[mf][r];

    if (t + 1 < SEQ) {
      #pragma unroll
      for (int mf = 0; mf < 2; ++mf)
        #pragma unroll
        for (int r = 0; r < 4; ++r)
          xwreg[mf][r] = out[((size_t)(t + 1) * NB + rowBase + mf * 16 + r0 + r) * NH + colC];

      // ---- poll: all 128 wave-flags of this bg, 2 per lane ----
      const unsigned tgt = (unsigned)(t + 1);
      const u64* fp = (const u64*)flags + pollIdx;
      u64 fv;
      do {
        fv = __hip_atomic_load(fp, __ATOMIC_RELAXED, __HIP_MEMORY_SCOPE_AGENT);
      } while (__any(((unsigned)fv < tgt) | ((unsigned)(fv >> 32) < tgt)));
      __builtin_amdgcn_sched_barrier(0);
    }
  }
}

extern "C" void kernel_launch(void* const* d_in, const int* in_sizes, int n_in,
                              void* d_out, int out_size, void* d_ws, size_t ws_size,
                              hipStream_t stream) {
  const float* x    = (const float*)d_in[0];
  const float* s0   = (const float*)d_in[1];
  const float* wx   = (const float*)d_in[2];
  const float* wh   = (const float*)d_in[3];
  const float* bias = (const float*)d_in[4];
  float* out = (float*)d_out;

  char* ws = (char*)d_ws;
  unsigned short* whT   = (unsigned short*)(ws);                                  // 2 MB
  unsigned short* wxT   = (unsigned short*)(ws + (2u << 20));                     // 1 MB
  unsigned short* sb0   = (unsigned short*)(ws + (3u << 20));                     // 256 KB
  unsigned short* sb1   = (unsigned short*)(ws + (3u << 20) + (256u << 10));      // 256 KB
  unsigned int*   flags = (unsigned int*)(ws + (3u << 20) + (512u << 10));        // 2 KB

  (void)hipMemsetAsync(flags, 0, 2048, stream);
  k_cvt_whT<<<NH * NH / 256, 256, 0, stream>>>(wh, whT);
  k_cvt_wxT<<<NIN * NH / 256, 256, 0, stream>>>(wx, wxT);
  k_init_state<<<NB * NH / 256, 256, 0, stream>>>(s0, sb0);
  k_xw_gemm<<<(SEQ * NB / 128) * (NH / 128), 256, 0, stream>>>(x, wxT, bias, out);
  k_scan<<<64, 256, 0, stream>>>(whT, out, sb0, sb1, flags);
  (void)hipMemcpyAsync(out + (size_t)SEQ * NB * NH, out + (size_t)(SEQ - 1) * NB * NH,
                 (size_t)NB * NH * sizeof(float), hipMemcpyDeviceToDevice, stream);
}

// Round 8
// 3236.460 us; speedup vs baseline: 1.6062x; 1.6062x over previous
//
#include <hip/hip_runtime.h>
#include <hip/hip_bf16.h>
#include <math.h>

#define SEQ 512
#define NB  128
#define NIN 512
#define NH  1024

typedef __attribute__((ext_vector_type(8))) short short8;
typedef __attribute__((ext_vector_type(4))) float f32x4;
typedef __attribute__((ext_vector_type(4))) unsigned int u32x4;
typedef unsigned long long u64;

__device__ __forceinline__ unsigned short bf16b(float f) {
  __hip_bfloat16 h = __float2bfloat16(f);
  return *reinterpret_cast<unsigned short*>(&h);
}
__device__ __forceinline__ short8 cvt8(u32x4 u) { return __builtin_bit_cast(short8, u); }

// ---- Wh fp32 [NH][NH] -> WhT bf16 [c][k] ----
__global__ void k_cvt_whT(const float* __restrict__ wh, unsigned short* __restrict__ whT) {
  int idx = blockIdx.x * 256 + threadIdx.x;
  int k = idx >> 10, c = idx & (NH - 1);
  whT[(size_t)c * NH + k] = bf16b(wh[idx]);
}

// ---- Wx fp32 [NIN][NH] -> WxT bf16 [c][k] ----
__global__ void k_cvt_wxT(const float* __restrict__ wx, unsigned short* __restrict__ wxT) {
  int idx = blockIdx.x * 256 + threadIdx.x;
  int k = idx >> 10, c = idx & (NH - 1);
  wxT[(size_t)c * NIN + k] = bf16b(wx[idx]);
}

// ---- initial_state fp32 [NB][NH] -> fragment-packed bf16 state (layout v1) ----
__global__ void k_init_state(const float* __restrict__ s0, unsigned short* __restrict__ sbuf) {
  int idx = blockIdx.x * 256 + threadIdx.x;
  int row = idx >> 10, k = idx & (NH - 1);
  int mg = row >> 4, kc = k >> 5, g = (k & 31) >> 3, i = k & 7;
  int ln = (row & 15) | (g << 4);
  sbuf[((size_t)(mg * 32 + kc) * 64 + ln) * 8 + i] = bf16b(s0[idx]);
}

// ---- Phase 1: xw = input @ Wx + bias  -> fp32 into d_out states region ----
__launch_bounds__(256)
__global__ void k_xw_gemm(const float* __restrict__ x, const unsigned short* __restrict__ wxT,
                          const float* __restrict__ bias, float* __restrict__ out) {
  __shared__ unsigned short a_lds[128 * 40];
  __shared__ unsigned short b_lds[128 * 40];
  const int bx = blockIdx.x;
  const int n0 = (bx & 7) * 128;
  const int m0 = (bx >> 3) * 128;
  const int tid = threadIdx.x, lane = tid & 63, w = tid >> 6;
  const int wr = w >> 1, wc = w & 1;
  f32x4 acc[4][4] = {};
  for (int k0 = 0; k0 < NIN; k0 += 32) {
    {
      int j = tid & 7, rr = tid >> 3;
      #pragma unroll
      for (int p = 0; p < 4; ++p) {
        int row = p * 32 + rr;
        const float4 v = *reinterpret_cast<const float4*>(&x[(size_t)(m0 + row) * NIN + k0 + 4 * j]);
        unsigned int lo = bf16b(v.x) | ((unsigned int)bf16b(v.y) << 16);
        unsigned int hi = bf16b(v.z) | ((unsigned int)bf16b(v.w) << 16);
        *reinterpret_cast<uint2*>(&a_lds[row * 40 + 4 * j]) = make_uint2(lo, hi);
      }
    }
    {
      #pragma unroll
      for (int p = 0; p < 2; ++p) {
        int tt = p * 256 + tid;
        int col = tt >> 2, ko = (tt & 3) * 8;
        const uint4 v = *reinterpret_cast<const uint4*>(&wxT[(size_t)(n0 + col) * NIN + k0 + ko]);
        *reinterpret_cast<uint4*>(&b_lds[col * 40 + ko]) = v;
      }
    }
    __syncthreads();
    short8 af[4], bf[4];
    #pragma unroll
    for (int bi = 0; bi < 4; ++bi)
      af[bi] = *reinterpret_cast<const short8*>(&a_lds[(wr * 64 + bi * 16 + (lane & 15)) * 40 + (lane >> 4) * 8]);
    #pragma unroll
    for (int bj = 0; bj < 4; ++bj)
      bf[bj] = *reinterpret_cast<const short8*>(&b_lds[(wc * 64 + bj * 16 + (lane & 15)) * 40 + (lane >> 4) * 8]);
    #pragma unroll
    for (int bi = 0; bi < 4; ++bi) {
      #pragma unroll
      for (int bj = 0; bj < 4; ++bj)
        acc[bi][bj] = __builtin_amdgcn_mfma_f32_16x16x32_bf16(af[bi], bf[bj], acc[bi][bj], 0, 0, 0);
    }
    __syncthreads();
  }
  #pragma unroll
  for (int bi = 0; bi < 4; ++bi) {
    #pragma unroll
    for (int bj = 0; bj < 4; ++bj) {
      int col = n0 + wc * 64 + bj * 16 + (lane & 15);
      float bv = bias[col];
      #pragma unroll
      for (int r = 0; r < 4; ++r) {
        int row = m0 + wr * 64 + bi * 16 + (lane >> 4) * 4 + r;
        out[(size_t)row * NH + col] = acc[bi][bj][r] + bv;
      }
    }
  }
}

// One self-accounting chunk: 16 coherent 16B loads (+ optional wait for PREVIOUS chunk).
// Early-clobber outputs: load results may NOT alias the address registers.
#define LOAD_CHUNK(g, WAITSTR) \
  asm volatile( \
    "global_load_dwordx4 %0, %16, %20 sc1\n\t" \
    "global_load_dwordx4 %1, %16, %20 offset:1024 sc1\n\t" \
    "global_load_dwordx4 %2, %16, %20 offset:2048 sc1\n\t" \
    "global_load_dwordx4 %3, %16, %20 offset:3072 sc1\n\t" \
    "global_load_dwordx4 %4, %17, %20 sc1\n\t" \
    "global_load_dwordx4 %5, %17, %20 offset:1024 sc1\n\t" \
    "global_load_dwordx4 %6, %17, %20 offset:2048 sc1\n\t" \
    "global_load_dwordx4 %7, %17, %20 offset:3072 sc1\n\t" \
    "global_load_dwordx4 %8, %18, %20 sc1\n\t" \
    "global_load_dwordx4 %9, %18, %20 offset:1024 sc1\n\t" \
    "global_load_dwordx4 %10, %18, %20 offset:2048 sc1\n\t" \
    "global_load_dwordx4 %11, %18, %20 offset:3072 sc1\n\t" \
    "global_load_dwordx4 %12, %19, %20 sc1\n\t" \
    "global_load_dwordx4 %13, %19, %20 offset:1024 sc1\n\t" \
    "global_load_dwordx4 %14, %19, %20 offset:2048 sc1\n\t" \
    "global_load_dwordx4 %15, %19, %20 offset:3072 sc1\n\t" \
    WAITSTR \
    : "=&v"(a0[8*(g)+0]), "=&v"(a0[8*(g)+1]), "=&v"(a0[8*(g)+2]), "=&v"(a0[8*(g)+3]), \
      "=&v"(a0[8*(g)+4]), "=&v"(a0[8*(g)+5]), "=&v"(a0[8*(g)+6]), "=&v"(a0[8*(g)+7]), \
      "=&v"(a1[8*(g)+0]), "=&v"(a1[8*(g)+1]), "=&v"(a1[8*(g)+2]), "=&v"(a1[8*(g)+3]), \
      "=&v"(a1[8*(g)+4]), "=&v"(a1[8*(g)+5]), "=&v"(a1[8*(g)+6]), "=&v"(a1[8*(g)+7]) \
    : "v"(voffA[2*(g)]), "v"(voffA[2*(g)+1]), "v"(voffB[2*(g)]), "v"(voffB[2*(g)+1]), \
      "s"(curU) \
    : "memory")

#define MM(kc) \
  do { if ((kc) & 1) { \
         accO0 = __builtin_amdgcn_mfma_f32_16x16x32_bf16(cvt8(a0[(kc)]), cvt8(breg[(kc)]), accO0, 0, 0, 0); \
         accO1 = __builtin_amdgcn_mfma_f32_16x16x32_bf16(cvt8(a1[(kc)]), cvt8(breg[(kc)]), accO1, 0, 0, 0); \
       } else { \
         accE0 = __builtin_amdgcn_mfma_f32_16x16x32_bf16(cvt8(a0[(kc)]), cvt8(breg[(kc)]), accE0, 0, 0, 0); \
         accE1 = __builtin_amdgcn_mfma_f32_16x16x32_bf16(cvt8(a1[(kc)]), cvt8(breg[(kc)]), accE1, 0, 0, 0); \
       } } while (0)

#define MFMA_GROUP(g) \
  do { MM(8*(g)+0); MM(8*(g)+1); MM(8*(g)+2); MM(8*(g)+3); \
       MM(8*(g)+4); MM(8*(g)+5); MM(8*(g)+6); MM(8*(g)+7); } while (0)

// ---- Phase 2: persistent scan. Wave = 32 rows x 16 cols; Wh register-stationary.
// A-path: 4 self-accounting asm chunks, MFMA overlapped; fence/stores/flags = r6-proven.
__launch_bounds__(256, 1)
__global__ void k_scan(const unsigned short* __restrict__ whT,
                       float* __restrict__ out,
                       unsigned short* __restrict__ sb0,
                       unsigned short* __restrict__ sb1,
                       unsigned int* __restrict__ flags) {
  __shared__ unsigned short r_lds[4 * 512];   // 1KB per wave, wave-local repack
  const int bx = blockIdx.x;
  const int bg = bx >> 5;    // batch group: 64 rows
  const int cg = bx & 31;    // column group: 32 cols
  const int tid = threadIdx.x, lane = tid & 63, w = tid >> 6;
  const int rg = w >> 1;     // row half within block
  const int cgl = w & 1;     // col half within block
  const int c0 = lane & 15, r0 = (lane >> 4) * 4;

  // ---- persistent B: this wave's 16 cols x K=1024, 128 VGPRs ----
  u32x4 breg[32];
  const int colC = cg * 32 + cgl * 16 + c0;
  {
    const unsigned short* bp = whT + (size_t)colC * NH + (lane >> 4) * 8;
    #pragma unroll
    for (int kc = 0; kc < 32; ++kc)
      breg[kc] = *reinterpret_cast<const u32x4*>(bp + kc * 32);
  }

  const int mgA = bg * 4 + rg * 2;   // first of wave's two m-groups
  unsigned int voffA[8], voffB[8];
  #pragma unroll
  for (int kcg = 0; kcg < 8; ++kcg) {
    voffA[kcg] = (unsigned)((mgA * 32 + kcg * 4) * 1024 + lane * 16);   // bytes, mf=0
    voffB[kcg] = voffA[kcg] + 32768u;                                    // mf=1
  }
  const int ldsRdU = w * 512 + (lane >> 5) * 256 + (lane & 31) * 8;    // ushort idx
  const size_t sIdx64 = (size_t)((mgA + (lane >> 5)) * 32 + cg) * 128 + (cgl * 32 + (lane & 31)) * 2;
  const int flagIdx = bg * 256 + cg * 4 + w;             // dword idx
  const int pollIdx = bg * 128 + lane;                   // u64 idx (2 flags/lane)
  const int rowBase = bg * 64 + rg * 32;

  // prologue: xw for t=0
  float xwreg[2][4];
  #pragma unroll
  for (int mf = 0; mf < 2; ++mf)
    #pragma unroll
    for (int r = 0; r < 4; ++r)
      xwreg[mf][r] = out[(size_t)(rowBase + mf * 16 + r0 + r) * NH + colC];

  #pragma unroll 1
  for (int t = 0; t < SEQ; ++t) {
    const unsigned long long curU = (unsigned long long)((t & 1) ? sb1 : sb0);
    u64* nxt64 = (u64*)((t & 1) ? sb0 : sb1);

    u32x4 a0[32], a1[32];
    f32x4 accE0 = {0.f,0.f,0.f,0.f}, accO0 = {0.f,0.f,0.f,0.f};
    f32x4 accE1 = {0.f,0.f,0.f,0.f}, accO1 = {0.f,0.f,0.f,0.f};

    // chunk pipeline: issue g+1, wait for g (in-order vmcnt retirement), MFMA g
    LOAD_CHUNK(0, "");
    LOAD_CHUNK(1, "s_waitcnt vmcnt(16)");
    __builtin_amdgcn_sched_barrier(0);
    MFMA_GROUP(0);
    LOAD_CHUNK(2, "s_waitcnt vmcnt(16)");
    __builtin_amdgcn_sched_barrier(0);
    MFMA_GROUP(1);
    LOAD_CHUNK(3, "s_waitcnt vmcnt(16)");
    __builtin_amdgcn_sched_barrier(0);
    MFMA_GROUP(2);
    asm volatile("s_waitcnt vmcnt(0)" ::: "memory");
    __builtin_amdgcn_sched_barrier(0);
    MFMA_GROUP(3);

    // ---- tanh + wave-local LDS repack write ----
    float vout[2][4];
    const int gc = c0 >> 3;
    #pragma unroll
    for (int mf = 0; mf < 2; ++mf) {
      const f32x4 s = (mf ? accE1 : accE0) + (mf ? accO1 : accO0);
      #pragma unroll
      for (int r = 0; r < 4; ++r) {
        float pre = s[r] + xwreg[mf][r];
        float e = __expf(2.0f * pre);
        float v = 1.0f - __fdividef(2.0f, e + 1.0f);
        vout[mf][r] = v;
        r_lds[w * 512 + mf * 256 + (((r0 + r) | (gc << 4)) << 3) + (c0 & 7)] = bf16b(v);
      }
    }
    // ordering fence between ushort repack-writes and u64 repack-read (r6-proven)
    __syncthreads();
    const u64* rl = reinterpret_cast<const u64*>(&r_lds[ldsRdU]);
    u64 sd0 = rl[0], sd1 = rl[1];

    // ---- coherent state store, drain, flag ----
    __hip_atomic_store(nxt64 + sIdx64,     sd0, __ATOMIC_RELAXED, __HIP_MEMORY_SCOPE_AGENT);
    __hip_atomic_store(nxt64 + sIdx64 + 1, sd1, __ATOMIC_RELAXED, __HIP_MEMORY_SCOPE_AGENT);
    asm volatile("s_waitcnt vmcnt(0)" ::: "memory");
    if (t + 1 < SEQ) {
      if (lane == 0)
        __hip_atomic_store(flags + flagIdx, (unsigned)(t + 1),
                           __ATOMIC_RELAXED, __HIP_MEMORY_SCOPE_AGENT);
    }

    // ---- fp32 out stores + xw[t+1] prefetch (hidden in poll window) ----
    #pragma unroll
    for (int mf = 0; mf < 2; ++mf)
      #pragma unroll
      for (int r = 0; r < 4; ++r)
        out[((size_t)t * NB + rowBase + mf * 16 + r0 + r) * NH + colC] = vout[mf][r];

    if (t + 1 < SEQ) {
      #pragma unroll
      for (int mf = 0; mf < 2; ++mf)
        #pragma unroll
        for (int r = 0; r < 4; ++r)
          xwreg[mf][r] = out[((size_t)(t + 1) * NB + rowBase + mf * 16 + r0 + r) * NH + colC];

      // ---- poll: all 128 wave-flags of this bg, 2 per lane ----
      const unsigned tgt = (unsigned)(t + 1);
      const u64* fp = (const u64*)flags + pollIdx;
      u64 fv;
      do {
        fv = __hip_atomic_load(fp, __ATOMIC_RELAXED, __HIP_MEMORY_SCOPE_AGENT);
      } while (__any(((unsigned)fv < tgt) | ((unsigned)(fv >> 32) < tgt)));
      __builtin_amdgcn_sched_barrier(0);
    }
  }
}

extern "C" void kernel_launch(void* const* d_in, const int* in_sizes, int n_in,
                              void* d_out, int out_size, void* d_ws, size_t ws_size,
                              hipStream_t stream) {
  const float* x    = (const float*)d_in[0];
  const float* s0   = (const float*)d_in[1];
  const float* wx   = (const float*)d_in[2];
  const float* wh   = (const float*)d_in[3];
  const float* bias = (const float*)d_in[4];
  float* out = (float*)d_out;

  char* ws = (char*)d_ws;
  unsigned short* whT   = (unsigned short*)(ws);                                  // 2 MB
  unsigned short* wxT   = (unsigned short*)(ws + (2u << 20));                     // 1 MB
  unsigned short* sb0   = (unsigned short*)(ws + (3u << 20));                     // 256 KB
  unsigned short* sb1   = (unsigned short*)(ws + (3u << 20) + (256u << 10));      // 256 KB
  unsigned int*   flags = (unsigned int*)(ws + (3u << 20) + (512u << 10));        // 2 KB

  (void)hipMemsetAsync(flags, 0, 2048, stream);
  k_cvt_whT<<<NH * NH / 256, 256, 0, stream>>>(wh, whT);
  k_cvt_wxT<<<NIN * NH / 256, 256, 0, stream>>>(wx, wxT);
  k_init_state<<<NB * NH / 256, 256, 0, stream>>>(s0, sb0);
  k_xw_gemm<<<(SEQ * NB / 128) * (NH / 128), 256, 0, stream>>>(x, wxT, bias, out);
  k_scan<<<64, 256, 0, stream>>>(whT, out, sb0, sb1, flags);
  (void)hipMemcpyAsync(out + (size_t)SEQ * NB * NH, out + (size_t)(SEQ - 1) * NB * NH,
                 (size_t)NB * NH * sizeof(float), hipMemcpyDeviceToDevice, stream);
}

// Round 10
// 3235.841 us; speedup vs baseline: 1.6066x; 1.0002x over previous
//
#include <hip/hip_runtime.h>
#include <hip/hip_bf16.h>
#include <math.h>

#define SEQ 512
#define NB  128
#define NIN 512
#define NH  1024

typedef __attribute__((ext_vector_type(8))) short short8;
typedef __attribute__((ext_vector_type(4))) float f32x4;
typedef __attribute__((ext_vector_type(4))) unsigned int u32x4;
typedef unsigned long long u64;

__device__ __forceinline__ unsigned short bf16b(float f) {
  __hip_bfloat16 h = __float2bfloat16(f);
  return *reinterpret_cast<unsigned short*>(&h);
}
__device__ __forceinline__ short8 cvt8(u32x4 u) { return __builtin_bit_cast(short8, u); }

// ---- Wh fp32 [NH][NH] -> WhT bf16 [c][k] ----
__global__ void k_cvt_whT(const float* __restrict__ wh, unsigned short* __restrict__ whT) {
  int idx = blockIdx.x * 256 + threadIdx.x;
  int k = idx >> 10, c = idx & (NH - 1);
  whT[(size_t)c * NH + k] = bf16b(wh[idx]);
}

// ---- Wx fp32 [NIN][NH] -> WxT bf16 [c][k] ----
__global__ void k_cvt_wxT(const float* __restrict__ wx, unsigned short* __restrict__ wxT) {
  int idx = blockIdx.x * 256 + threadIdx.x;
  int k = idx >> 10, c = idx & (NH - 1);
  wxT[(size_t)c * NIN + k] = bf16b(wx[idx]);
}

// ---- initial_state fp32 [NB][NH] -> fragment-packed bf16 state (layout v1) ----
__global__ void k_init_state(const float* __restrict__ s0, unsigned short* __restrict__ sbuf) {
  int idx = blockIdx.x * 256 + threadIdx.x;
  int row = idx >> 10, k = idx & (NH - 1);
  int mg = row >> 4, kc = k >> 5, g = (k & 31) >> 3, i = k & 7;
  int ln = (row & 15) | (g << 4);
  sbuf[((size_t)(mg * 32 + kc) * 64 + ln) * 8 + i] = bf16b(s0[idx]);
}

// ---- Phase 1: xw = input @ Wx + bias  -> fp32 into d_out states region ----
__launch_bounds__(256)
__global__ void k_xw_gemm(const float* __restrict__ x, const unsigned short* __restrict__ wxT,
                          const float* __restrict__ bias, float* __restrict__ out) {
  __shared__ unsigned short a_lds[128 * 40];
  __shared__ unsigned short b_lds[128 * 40];
  const int bx = blockIdx.x;
  const int n0 = (bx & 7) * 128;
  const int m0 = (bx >> 3) * 128;
  const int tid = threadIdx.x, lane = tid & 63, w = tid >> 6;
  const int wr = w >> 1, wc = w & 1;
  f32x4 acc[4][4] = {};
  for (int k0 = 0; k0 < NIN; k0 += 32) {
    {
      int j = tid & 7, rr = tid >> 3;
      #pragma unroll
      for (int p = 0; p < 4; ++p) {
        int row = p * 32 + rr;
        const float4 v = *reinterpret_cast<const float4*>(&x[(size_t)(m0 + row) * NIN + k0 + 4 * j]);
        unsigned int lo = bf16b(v.x) | ((unsigned int)bf16b(v.y) << 16);
        unsigned int hi = bf16b(v.z) | ((unsigned int)bf16b(v.w) << 16);
        *reinterpret_cast<uint2*>(&a_lds[row * 40 + 4 * j]) = make_uint2(lo, hi);
      }
    }
    {
      #pragma unroll
      for (int p = 0; p < 2; ++p) {
        int tt = p * 256 + tid;
        int col = tt >> 2, ko = (tt & 3) * 8;
        const uint4 v = *reinterpret_cast<const uint4*>(&wxT[(size_t)(n0 + col) * NIN + k0 + ko]);
        *reinterpret_cast<uint4*>(&b_lds[col * 40 + ko]) = v;
      }
    }
    __syncthreads();
    short8 af[4], bf[4];
    #pragma unroll
    for (int bi = 0; bi < 4; ++bi)
      af[bi] = *reinterpret_cast<const short8*>(&a_lds[(wr * 64 + bi * 16 + (lane & 15)) * 40 + (lane >> 4) * 8]);
    #pragma unroll
    for (int bj = 0; bj < 4; ++bj)
      bf[bj] = *reinterpret_cast<const short8*>(&b_lds[(wc * 64 + bj * 16 + (lane & 15)) * 40 + (lane >> 4) * 8]);
    #pragma unroll
    for (int bi = 0; bi < 4; ++bi) {
      #pragma unroll
      for (int bj = 0; bj < 4; ++bj)
        acc[bi][bj] = __builtin_amdgcn_mfma_f32_16x16x32_bf16(af[bi], bf[bj], acc[bi][bj], 0, 0, 0);
    }
    __syncthreads();
  }
  #pragma unroll
  for (int bi = 0; bi < 4; ++bi) {
    #pragma unroll
    for (int bj = 0; bj < 4; ++bj) {
      int col = n0 + wc * 64 + bj * 16 + (lane & 15);
      float bv = bias[col];
      #pragma unroll
      for (int r = 0; r < 4; ++r) {
        int row = m0 + wr * 64 + bi * 16 + (lane >> 4) * 4 + r;
        out[(size_t)row * NH + col] = acc[bi][bj][r] + bv;
      }
    }
  }
}

// One self-accounting A chunk: 16 coherent 16B loads (+ optional wait for PREVIOUS chunk).
#define LOAD_CHUNK(g, WAITSTR) \
  asm volatile( \
    "global_load_dwordx4 %0, %16, %20 sc1\n\t" \
    "global_load_dwordx4 %1, %16, %20 offset:1024 sc1\n\t" \
    "global_load_dwordx4 %2, %16, %20 offset:2048 sc1\n\t" \
    "global_load_dwordx4 %3, %16, %20 offset:3072 sc1\n\t" \
    "global_load_dwordx4 %4, %17, %20 sc1\n\t" \
    "global_load_dwordx4 %5, %17, %20 offset:1024 sc1\n\t" \
    "global_load_dwordx4 %6, %17, %20 offset:2048 sc1\n\t" \
    "global_load_dwordx4 %7, %17, %20 offset:3072 sc1\n\t" \
    "global_load_dwordx4 %8, %18, %20 sc1\n\t" \
    "global_load_dwordx4 %9, %18, %20 offset:1024 sc1\n\t" \
    "global_load_dwordx4 %10, %18, %20 offset:2048 sc1\n\t" \
    "global_load_dwordx4 %11, %18, %20 offset:3072 sc1\n\t" \
    "global_load_dwordx4 %12, %19, %20 sc1\n\t" \
    "global_load_dwordx4 %13, %19, %20 offset:1024 sc1\n\t" \
    "global_load_dwordx4 %14, %19, %20 offset:2048 sc1\n\t" \
    "global_load_dwordx4 %15, %19, %20 offset:3072 sc1\n\t" \
    WAITSTR \
    : "=&v"(a0[8*(g)+0]), "=&v"(a0[8*(g)+1]), "=&v"(a0[8*(g)+2]), "=&v"(a0[8*(g)+3]), \
      "=&v"(a0[8*(g)+4]), "=&v"(a0[8*(g)+5]), "=&v"(a0[8*(g)+6]), "=&v"(a0[8*(g)+7]), \
      "=&v"(a1[8*(g)+0]), "=&v"(a1[8*(g)+1]), "=&v"(a1[8*(g)+2]), "=&v"(a1[8*(g)+3]), \
      "=&v"(a1[8*(g)+4]), "=&v"(a1[8*(g)+5]), "=&v"(a1[8*(g)+6]), "=&v"(a1[8*(g)+7]) \
    : "v"(voffA[2*(g)]), "v"(voffA[2*(g)+1]), "v"(voffB[2*(g)]), "v"(voffB[2*(g)+1]), \
      "s"(curU) \
    : "memory")

#define MM(kc) \
  do { if ((kc) & 1) { \
         accO0 = __builtin_amdgcn_mfma_f32_16x16x32_bf16(cvt8(a0[(kc)]), cvt8(breg[(kc)]), accO0, 0, 0, 0); \
         accO1 = __builtin_amdgcn_mfma_f32_16x16x32_bf16(cvt8(a1[(kc)]), cvt8(breg[(kc)]), accO1, 0, 0, 0); \
       } else { \
         accE0 = __builtin_amdgcn_mfma_f32_16x16x32_bf16(cvt8(a0[(kc)]), cvt8(breg[(kc)]), accE0, 0, 0, 0); \
         accE1 = __builtin_amdgcn_mfma_f32_16x16x32_bf16(cvt8(a1[(kc)]), cvt8(breg[(kc)]), accE1, 0, 0, 0); \
       } } while (0)

#define MFMA_GROUP(g) \
  do { MM(8*(g)+0); MM(8*(g)+1); MM(8*(g)+2); MM(8*(g)+3); \
       MM(8*(g)+4); MM(8*(g)+5); MM(8*(g)+6); MM(8*(g)+7); } while (0)

// ---- Phase 2: persistent scan. Wave = 32 rows x 16 cols; Wh register-stationary
// via ONE opaque asm (32 loads + internal vmcnt(0): no in-flight-output hazard).
__launch_bounds__(256, 1)
__global__ void k_scan(const unsigned short* __restrict__ whT,
                       float* __restrict__ out,
                       unsigned short* __restrict__ sb0,
                       unsigned short* __restrict__ sb1,
                       unsigned int* __restrict__ flags) {
  __shared__ unsigned short r_lds[4 * 512];   // 1KB per wave, wave-local repack
  const int bx = blockIdx.x;
  const int bg = bx >> 5;    // batch group: 64 rows
  const int cg = bx & 31;    // column group: 32 cols
  const int tid = threadIdx.x, lane = tid & 63, w = tid >> 6;
  const int rg = w >> 1;     // row half within block
  const int cgl = w & 1;     // col half within block
  const int c0 = lane & 15, r0 = (lane >> 4) * 4;
  const int colC = cg * 32 + cgl * 16 + c0;

  // ---- persistent B: 16 cols x K=1024 in 128 VGPRs, single opaque asm, wait inside ----
  u32x4 breg[32];
  {
    const unsigned long long whU = (unsigned long long)whT;
    const unsigned voffW = (unsigned)(((unsigned)colC * NH + ((unsigned)lane >> 4) * 8) * 2);
    asm volatile(
      "global_load_dwordx4 %0, %32, %33\n\t"
      "global_load_dwordx4 %1, %32, %33 offset:64\n\t"
      "global_load_dwordx4 %2, %32, %33 offset:128\n\t"
      "global_load_dwordx4 %3, %32, %33 offset:192\n\t"
      "global_load_dwordx4 %4, %32, %33 offset:256\n\t"
      "global_load_dwordx4 %5, %32, %33 offset:320\n\t"
      "global_load_dwordx4 %6, %32, %33 offset:384\n\t"
      "global_load_dwordx4 %7, %32, %33 offset:448\n\t"
      "global_load_dwordx4 %8, %32, %33 offset:512\n\t"
      "global_load_dwordx4 %9, %32, %33 offset:576\n\t"
      "global_load_dwordx4 %10, %32, %33 offset:640\n\t"
      "global_load_dwordx4 %11, %32, %33 offset:704\n\t"
      "global_load_dwordx4 %12, %32, %33 offset:768\n\t"
      "global_load_dwordx4 %13, %32, %33 offset:832\n\t"
      "global_load_dwordx4 %14, %32, %33 offset:896\n\t"
      "global_load_dwordx4 %15, %32, %33 offset:960\n\t"
      "global_load_dwordx4 %16, %32, %33 offset:1024\n\t"
      "global_load_dwordx4 %17, %32, %33 offset:1088\n\t"
      "global_load_dwordx4 %18, %32, %33 offset:1152\n\t"
      "global_load_dwordx4 %19, %32, %33 offset:1216\n\t"
      "global_load_dwordx4 %20, %32, %33 offset:1280\n\t"
      "global_load_dwordx4 %21, %32, %33 offset:1344\n\t"
      "global_load_dwordx4 %22, %32, %33 offset:1408\n\t"
      "global_load_dwordx4 %23, %32, %33 offset:1472\n\t"
      "global_load_dwordx4 %24, %32, %33 offset:1536\n\t"
      "global_load_dwordx4 %25, %32, %33 offset:1600\n\t"
      "global_load_dwordx4 %26, %32, %33 offset:1664\n\t"
      "global_load_dwordx4 %27, %32, %33 offset:1728\n\t"
      "global_load_dwordx4 %28, %32, %33 offset:1792\n\t"
      "global_load_dwordx4 %29, %32, %33 offset:1856\n\t"
      "global_load_dwordx4 %30, %32, %33 offset:1920\n\t"
      "global_load_dwordx4 %31, %32, %33 offset:1984\n\t"
      "s_waitcnt vmcnt(0)"
      : "=&v"(breg[0]),  "=&v"(breg[1]),  "=&v"(breg[2]),  "=&v"(breg[3]),
        "=&v"(breg[4]),  "=&v"(breg[5]),  "=&v"(breg[6]),  "=&v"(breg[7]),
        "=&v"(breg[8]),  "=&v"(breg[9]),  "=&v"(breg[10]), "=&v"(breg[11]),
        "=&v"(breg[12]), "=&v"(breg[13]), "=&v"(breg[14]), "=&v"(breg[15]),
        "=&v"(breg[16]), "=&v"(breg[17]), "=&v"(breg[18]), "=&v"(breg[19]),
        "=&v"(breg[20]), "=&v"(breg[21]), "=&v"(breg[22]), "=&v"(breg[23]),
        "=&v"(breg[24]), "=&v"(breg[25]), "=&v"(breg[26]), "=&v"(breg[27]),
        "=&v"(breg[28]), "=&v"(breg[29]), "=&v"(breg[30]), "=&v"(breg[31])
      : "v"(voffW), "s"(whU)
      : "memory");
  }
  __builtin_amdgcn_sched_barrier(0);

  const int mgA = bg * 4 + rg * 2;   // first of wave's two m-groups
  unsigned int voffA[8], voffB[8];
  #pragma unroll
  for (int kcg = 0; kcg < 8; ++kcg) {
    voffA[kcg] = (unsigned)((mgA * 32 + kcg * 4) * 1024 + lane * 16);   // bytes, mf=0
    voffB[kcg] = voffA[kcg] + 32768u;                                    // mf=1
  }
  const int ldsRdU = w * 512 + (lane >> 5) * 256 + (lane & 31) * 8;    // ushort idx
  const size_t sIdx64 = (size_t)((mgA + (lane >> 5)) * 32 + cg) * 128 + (cgl * 32 + (lane & 31)) * 2;
  const int flagIdx = bg * 256 + cg * 4 + w;             // dword idx
  const int pollIdx = bg * 128 + lane;                   // u64 idx (2 flags/lane)
  const int rowBase = bg * 64 + rg * 32;

  // prologue: xw for t=0
  float xwreg[2][4];
  #pragma unroll
  for (int mf = 0; mf < 2; ++mf)
    #pragma unroll
    for (int r = 0; r < 4; ++r)
      xwreg[mf][r] = out[(size_t)(rowBase + mf * 16 + r0 + r) * NH + colC];

  #pragma unroll 1
  for (int t = 0; t < SEQ; ++t) {
    const unsigned long long curU = (unsigned long long)((t & 1) ? sb1 : sb0);
    u64* nxt64 = (u64*)((t & 1) ? sb0 : sb1);

    u32x4 a0[32], a1[32];
    f32x4 accE0 = {0.f,0.f,0.f,0.f}, accO0 = {0.f,0.f,0.f,0.f};
    f32x4 accE1 = {0.f,0.f,0.f,0.f}, accO1 = {0.f,0.f,0.f,0.f};

    // chunk pipeline: issue g+1, wait for g (in-order vmcnt retirement), MFMA g
    LOAD_CHUNK(0, "");
    LOAD_CHUNK(1, "s_waitcnt vmcnt(16)");
    __builtin_amdgcn_sched_barrier(0);
    MFMA_GROUP(0);
    LOAD_CHUNK(2, "s_waitcnt vmcnt(16)");
    __builtin_amdgcn_sched_barrier(0);
    MFMA_GROUP(1);
    LOAD_CHUNK(3, "s_waitcnt vmcnt(16)");
    __builtin_amdgcn_sched_barrier(0);
    MFMA_GROUP(2);
    asm volatile("s_waitcnt vmcnt(0)" ::: "memory");
    __builtin_amdgcn_sched_barrier(0);
    MFMA_GROUP(3);

    // ---- tanh + wave-local LDS repack write ----
    float vout[2][4];
    const int gc = c0 >> 3;
    #pragma unroll
    for (int mf = 0; mf < 2; ++mf) {
      const f32x4 s = (mf ? accE1 : accE0) + (mf ? accO1 : accO0);
      #pragma unroll
      for (int r = 0; r < 4; ++r) {
        float pre = s[r] + xwreg[mf][r];
        float e = __expf(2.0f * pre);
        float v = 1.0f - __fdividef(2.0f, e + 1.0f);
        vout[mf][r] = v;
        r_lds[w * 512 + mf * 256 + (((r0 + r) | (gc << 4)) << 3) + (c0 & 7)] = bf16b(v);
      }
    }
    // ordering fence between ushort repack-writes and u64 repack-read (r6-proven)
    __syncthreads();
    const u64* rl = reinterpret_cast<const u64*>(&r_lds[ldsRdU]);
    u64 sd0 = rl[0], sd1 = rl[1];

    // ---- coherent state store, drain, flag ----
    __hip_atomic_store(nxt64 + sIdx64,     sd0, __ATOMIC_RELAXED, __HIP_MEMORY_SCOPE_AGENT);
    __hip_atomic_store(nxt64 + sIdx64 + 1, sd1, __ATOMIC_RELAXED, __HIP_MEMORY_SCOPE_AGENT);
    asm volatile("s_waitcnt vmcnt(0)" ::: "memory");
    if (t + 1 < SEQ) {
      if (lane == 0)
        __hip_atomic_store(flags + flagIdx, (unsigned)(t + 1),
                           __ATOMIC_RELAXED, __HIP_MEMORY_SCOPE_AGENT);
    }

    // ---- fp32 out stores + xw[t+1] prefetch (hidden in poll window) ----
    #pragma unroll
    for (int mf = 0; mf < 2; ++mf)
      #pragma unroll
      for (int r = 0; r < 4; ++r)
        out[((size_t)t * NB + rowBase + mf * 16 + r0 + r) * NH + colC] = vout[mf][r];

    if (t + 1 < SEQ) {
      #pragma unroll
      for (int mf = 0; mf < 2; ++mf)
        #pragma unroll
        for (int r = 0; r < 4; ++r)
          xwreg[mf][r] = out[((size_t)(t + 1) * NB + rowBase + mf * 16 + r0 + r) * NH + colC];

      // ---- poll: all 128 wave-flags of this bg, 2 per lane ----
      const unsigned tgt = (unsigned)(t + 1);
      const u64* fp = (const u64*)flags + pollIdx;
      u64 fv;
      do {
        fv = __hip_atomic_load(fp, __ATOMIC_RELAXED, __HIP_MEMORY_SCOPE_AGENT);
      } while (__any(((unsigned)fv < tgt) | ((unsigned)(fv >> 32) < tgt)));
      __builtin_amdgcn_sched_barrier(0);
    }
  }
}

extern "C" void kernel_launch(void* const* d_in, const int* in_sizes, int n_in,
                              void* d_out, int out_size, void* d_ws, size_t ws_size,
                              hipStream_t stream) {
  const float* x    = (const float*)d_in[0];
  const float* s0   = (const float*)d_in[1];
  const float* wx   = (const float*)d_in[2];
  const float* wh   = (const float*)d_in[3];
  const float* bias = (const float*)d_in[4];
  float* out = (float*)d_out;

  char* ws = (char*)d_ws;
  unsigned short* whT   = (unsigned short*)(ws);                                  // 2 MB
  unsigned short* wxT   = (unsigned short*)(ws + (2u << 20));                     // 1 MB
  unsigned short* sb0   = (unsigned short*)(ws + (3u << 20));                     // 256 KB
  unsigned short* sb1   = (unsigned short*)(ws + (3u << 20) + (256u << 10));      // 256 KB
  unsigned int*   flags = (unsigned int*)(ws + (3u << 20) + (512u << 10));        // 2 KB

  (void)hipMemsetAsync(flags, 0, 2048, stream);
  k_cvt_whT<<<NH * NH / 256, 256, 0, stream>>>(wh, whT);
  k_cvt_wxT<<<NIN * NH / 256, 256, 0, stream>>>(wx, wxT);
  k_init_state<<<NB * NH / 256, 256, 0, stream>>>(s0, sb0);
  k_xw_gemm<<<(SEQ * NB / 128) * (NH / 128), 256, 0, stream>>>(x, wxT, bias, out);
  k_scan<<<64, 256, 0, stream>>>(whT, out, sb0, sb1, flags);
  (void)hipMemcpyAsync(out + (size_t)SEQ * NB * NH, out + (size_t)(SEQ - 1) * NB * NH,
                 (size_t)NB * NH * sizeof(float), hipMemcpyDeviceToDevice, stream);
}